// Round 5
// baseline (164.856 us; speedup 1.0000x reference)
//
#include <hip/hip_runtime.h>
#include <hip/hip_bf16.h>

typedef float f32x4 __attribute__((ext_vector_type(4)));
typedef short s16x8 __attribute__((ext_vector_type(8)));

#define NROWS 8192
#define KDIM  1024
#define BM 256
#define BN 256
#define BK 64
#define NKT (KDIM / BK)                  // 16 K-tiles
#define NTILE (NROWS / BM)               // 32 tile-rows
#define NBLK (NTILE * (NTILE + 1) / 2)   // 528 upper-tri blocks

#define WAITV(n) asm volatile("s_waitcnt vmcnt(" #n ")" ::: "memory")
#define LGKM(n)  asm volatile("s_waitcnt lgkmcnt(" #n ")" ::: "memory")
#define BARx do { asm volatile("" ::: "memory"); __builtin_amdgcn_s_barrier(); asm volatile("" ::: "memory"); } while (0)

// round-to-nearest-even fp32 -> bf16 bits, also returns the rounded-back fp32 value
__device__ __forceinline__ unsigned short f2bf(float f, float& back) {
    union { float f; unsigned u; } a; a.f = f;
    unsigned r = a.u + 0x7fffu + ((a.u >> 16) & 1u);
    unsigned short b = (unsigned short)(r >> 16);
    union { unsigned u; float f; } c; c.u = ((unsigned)b) << 16;
    back = c.f;
    return b;
}

__device__ __forceinline__ void gl_lds16(const unsigned short* g, unsigned short* l) {
    __builtin_amdgcn_global_load_lds(
        (const __attribute__((address_space(1))) void*)g,
        (__attribute__((address_space(3))) void*)l, 16, 0, 0);
}

__global__ __launch_bounds__(256)
void prep_kernel(const float* __restrict__ in, unsigned short* __restrict__ abf,
                 float* __restrict__ sq) {
    const int row = blockIdx.x;
    const int t = threadIdx.x;
    const float4 v = reinterpret_cast<const float4*>(in + (size_t)row * KDIM)[t];
    float b0, b1, b2, b3;
    ushort4 u;
    u.x = f2bf(v.x, b0);
    u.y = f2bf(v.y, b1);
    u.z = f2bf(v.z, b2);
    u.w = f2bf(v.w, b3);
    reinterpret_cast<ushort4*>(abf + (size_t)row * KDIM)[t] = u;
    float s = b0 * b0 + b1 * b1 + b2 * b2 + b3 * b3;
    #pragma unroll
    for (int off = 32; off > 0; off >>= 1) s += __shfl_down(s, off);
    __shared__ float red[4];
    if ((t & 63) == 0) red[t >> 6] = s;
    __syncthreads();
    if (t == 0) sq[row] = red[0] + red[1] + red[2] + red[3];
}

// ---- 8-phase 256x256 GEMM (m201-style), C = A*A^T upper-tri tiles ----
// 8 waves (2M x 4N), per-wave 128x64 output, BK=64, 2 K-tiles per loop iter.
// LDS 128 KiB: [buf][A/B][half][sub][kk][512] -- fragment-major 1KB blocks so
// both gl_lds writes and ds_read_b128 reads are linear (conflict-free); the
// fragment permutation is baked into per-lane GLOBAL source addresses (m173).
// Per K-tile 4 phases; stages: P1 -> t+1:A-half1, P2/P3/P4 -> t+2:A0/B0/B1.
// vmcnt(6) only at phase 4 (3 half-tiles in flight); prologue 4+3 halves with
// vmcnt(4)/vmcnt(6); epilogue vmcnt(0) at tile NKT-2.
__global__ __launch_bounds__(512, 2)
void gemm_kernel(const unsigned short* __restrict__ A, const float* __restrict__ sq,
                 float* __restrict__ out) {
    __shared__ __attribute__((aligned(16))) unsigned short lds[2][2][2][8][2][512];

    // XCD-aware swizzle: 528 % 8 == 0 -> bijective
    const int bid = blockIdx.x;
    const int cpx = NBLK >> 3;  // 66
    const int swz = (bid & 7) * cpx + (bid >> 3);

    // triangular decode: swz -> (bi, bj), bi <= bj; tiles in rows < r: r*(65-r)/2
    int bi = (int)((65.0f - sqrtf(65.0f * 65.0f - 8.0f * (float)swz)) * 0.5f);
    if (bi > NTILE - 1) bi = NTILE - 1;
    if (bi < 0) bi = 0;
    while ((bi + 1) * (65 - (bi + 1)) / 2 <= swz) ++bi;
    while (bi * (65 - bi) / 2 > swz) --bi;
    const int bj = bi + (swz - bi * (65 - bi) / 2);

    const int brow = bi * BM;
    const int bcol = bj * BN;

    const int t = threadIdx.x;       // 0..511
    const int lane = t & 63;
    const int w = t >> 6;            // 0..7
    const int wr = w >> 2;           // 0..1 -> rows wr*128..+127
    const int wc = w & 3;            // 0..3 -> cols wc*64..+63
    const int l15 = lane & 15, l4 = lane >> 4;

    // staging roles: wave w owns sub=w of each half. f/g formulas invert the
    // read-side mapping (A: sub = m + wr*4, half = mh; B: sub = n' + wc*2).
    const int fA0 = (w & 3) + (w >> 2) * 8;        // A half0 row-frag
    const int fA1 = fA0 + 4;                       // A half1
    const int gB0 = (w & 1) + ((w >> 1) & 3) * 4;  // B half0 col-frag
    const int gB1 = gB0 + 2;                       // B half1

    // per-lane global source (element ptrs); lane l -> row +(l&15), k +(l>>4)*8
    const unsigned short* pA0 = A + (size_t)(brow + fA0 * 16 + l15) * KDIM + l4 * 8;
    const unsigned short* pA1 = A + (size_t)(brow + fA1 * 16 + l15) * KDIM + l4 * 8;
    const unsigned short* pB0 = A + (size_t)(bcol + gB0 * 16 + l15) * KDIM + l4 * 8;
    const unsigned short* pB1 = A + (size_t)(bcol + gB1 * 16 + l15) * KDIM + l4 * 8;

#define LA(sb, h) (&lds[sb][0][h][w][0][0])
#define LB(sb, h) (&lds[sb][1][h][w][0][0])
#define STG(p, off, d) do { gl_lds16((p) + (off), (d)); gl_lds16((p) + (off) + 32, (d) + 512); } while (0)

    f32x4 acc[8][4] = {};
    s16x8 aF[4][2], bF0[2][2], bF1[2][2];

#define RD_A(BUF, MH) do { \
    _Pragma("unroll") for (int m_ = 0; m_ < 4; ++m_) \
    _Pragma("unroll") for (int k_ = 0; k_ < 2; ++k_) \
        aF[m_][k_] = *reinterpret_cast<const s16x8*>(&lds[BUF][0][MH][wr * 4 + m_][k_][lane * 8]); \
} while (0)

#define RD_B(BUF, NH, BF) do { \
    _Pragma("unroll") for (int n_ = 0; n_ < 2; ++n_) \
    _Pragma("unroll") for (int k_ = 0; k_ < 2; ++k_) \
        BF[n_][k_] = *reinterpret_cast<const s16x8*>(&lds[BUF][1][NH][wc * 2 + n_][k_][lane * 8]); \
} while (0)

#define MFMA_Q(MH, NH, BF) do { \
    _Pragma("unroll") for (int m_ = 0; m_ < 4; ++m_) \
    _Pragma("unroll") for (int n_ = 0; n_ < 2; ++n_) { \
        acc[(MH)*4 + m_][(NH)*2 + n_] = __builtin_amdgcn_mfma_f32_16x16x32_bf16(aF[m_][0], BF[n_][0], acc[(MH)*4 + m_][(NH)*2 + n_], 0, 0, 0); \
        acc[(MH)*4 + m_][(NH)*2 + n_] = __builtin_amdgcn_mfma_f32_16x16x32_bf16(aF[m_][1], BF[n_][1], acc[(MH)*4 + m_][(NH)*2 + n_], 0, 0, 0); \
    } \
} while (0)

#define TILE(BUF, S1, S2, S3, S4, VMW) do { \
    /* P1 */ \
    RD_A(BUF, 0); RD_B(BUF, 0, bF0); \
    S1; \
    LGKM(8); \
    BARx; LGKM(0); \
    __builtin_amdgcn_s_setprio(1); MFMA_Q(0, 0, bF0); __builtin_amdgcn_s_setprio(0); \
    BARx; \
    /* P2 */ \
    RD_B(BUF, 1, bF1); \
    S2; \
    BARx; LGKM(0); \
    __builtin_amdgcn_s_setprio(1); MFMA_Q(0, 1, bF1); __builtin_amdgcn_s_setprio(0); \
    BARx; \
    /* P3 */ \
    RD_A(BUF, 1); \
    S3; \
    BARx; LGKM(0); \
    __builtin_amdgcn_s_setprio(1); MFMA_Q(1, 1, bF1); __builtin_amdgcn_s_setprio(0); \
    BARx; \
    /* P4 */ \
    S4; \
    VMW; \
    BARx; LGKM(0); \
    __builtin_amdgcn_s_setprio(1); MFMA_Q(1, 0, bF0); __builtin_amdgcn_s_setprio(0); \
    BARx; \
} while (0)

    // ---- prologue: tile0 all 4 halves, vmcnt(4); tile1 3 halves, vmcnt(6) ----
    STG(pA0, 0, LA(0, 0)); STG(pB0, 0, LB(0, 0)); STG(pB1, 0, LB(0, 1)); STG(pA1, 0, LA(0, 1));
    WAITV(4);
    STG(pA0, 64, LA(1, 0)); STG(pB0, 64, LB(1, 0)); STG(pB1, 64, LB(1, 1));
    WAITV(6);
    BARx;
    // bias: A1-role next stages tile1 (+64); A0/B0/B1 next stage tile2 (+128)
    pA1 += 64; pA0 += 128; pB0 += 128; pB1 += 128;

    // ---- main loop: tiles 0..13 (2 per iter), fully steady ----
    for (int u = 0; u < 7; ++u) {
        TILE(0, STG(pA1, 0, LA(1, 1)), STG(pA0, 0, LA(0, 0)), STG(pB0, 0, LB(0, 0)), STG(pB1, 0, LB(0, 1)), WAITV(6));
        TILE(1, STG(pA1, 64, LA(0, 1)), STG(pA0, 64, LA(1, 0)), STG(pB0, 64, LB(1, 0)), STG(pB1, 64, LB(1, 1)), WAITV(6));
        pA1 += 128; pA0 += 128; pB0 += 128; pB1 += 128;
    }
    // ---- tile 14: stage tile15:A1 only; drain ----
    TILE(0, STG(pA1, 0, LA(1, 1)), ((void)0), ((void)0), ((void)0), WAITV(0));
    // ---- tile 15: no staging ----
    TILE(1, ((void)0), ((void)0), ((void)0), ((void)0), ((void)0));

    // ---- epilogue: C/D layout col = lane&15, row = (lane>>4)*4 + reg ----
    const int ib = brow + wr * 128 + l4 * 4;   // + m*16 + r
    const int jb = bcol + wc * 64 + l15;       // + n*16
    float sqj[4];
    #pragma unroll
    for (int n = 0; n < 4; ++n) sqj[n] = sq[jb + n * 16];

    const bool offdiag = (bi != bj);
    #pragma unroll
    for (int m = 0; m < 8; ++m) {
        #pragma unroll
        for (int n = 0; n < 4; ++n) {
            f32x4 tv;
            #pragma unroll
            for (int r = 0; r < 4; ++r) {
                const int i = ib + m * 16 + r;
                const float d2 = sq[i] + sqj[n] - 2.0f * acc[m][n][r];
                tv[r] = -sqrtf(fmaxf(d2, 0.0f));
            }
            #pragma unroll
            for (int r = 0; r < 4; ++r) {
                const int i = ib + m * 16 + r;
                out[(size_t)i * NROWS + (jb + n * 16)] = tv[r];
            }
            if (offdiag) {
                const size_t mrow = (size_t)(jb + n * 16) * NROWS + (ib + m * 16);
                *reinterpret_cast<float4*>(&out[mrow]) = *(float4*)&tv;
            }
        }
    }
}

extern "C" void kernel_launch(void* const* d_in, const int* in_sizes, int n_in,
                              void* d_out, int out_size, void* d_ws, size_t ws_size,
                              hipStream_t stream) {
    const float* feat = (const float*)d_in[0];
    float* out = (float*)d_out;
    unsigned short* abf = (unsigned short*)d_ws;                       // 16 MB bf16 copy
    float* sq = (float*)((char*)d_ws + (size_t)NROWS * KDIM * 2);      // 32 KB row sums

    prep_kernel<<<NROWS, 256, 0, stream>>>(feat, abf, sq);
    gemm_kernel<<<NBLK, 512, 0, stream>>>(abf, sq, out);
}